// Round 6
// baseline (857.356 us; speedup 1.0000x reference)
//
#include <hip/hip_runtime.h>
#include <hip/hip_bf16.h>

// ---------------------------------------------------------------------------
// GNNEncoder: 2x TransformerConv (heads=1) + ReLU.
// R6: node_attn is memory-traffic bound (R4 vs R5: same FETCH, 3x occupancy
// delta, same time). Halve the bytes:
//   - ea cast to bf16 once (82 MB vs 164 MB per layer)
//   - k,v emitted bf16 by pre_mfma, interleaved kv[N][256] (one 512B row/edge)
//   - skip buffer lives in d_out (saves workspace; same traffic)
// ---------------------------------------------------------------------------

#define D 128
#define ED 64

typedef short bf16x8 __attribute__((ext_vector_type(8)));
typedef float f32x4  __attribute__((ext_vector_type(4)));

static __device__ __forceinline__ unsigned short f2bf(float f) {
    unsigned int u = __float_as_uint(f);
    u = (u + 0x7fffu + ((u >> 16) & 1u)) >> 16;   // round-to-nearest-even
    return (unsigned short)u;
}
// unpack bf16 pair packed little-endian (lo = elem 2i, hi = elem 2i+1)
#define BF2(u, lo, hi) { lo = __uint_as_float((u) << 16); hi = __uint_as_float((u) & 0xffff0000u); }

// ---------------- fuse We into Wq: Wqe[i][c] = sum_j Wq[i][j]*We[c][j] -----
__global__ __launch_bounds__(128) void fuse_we_kernel(
    const float* __restrict__ Wq, const float* __restrict__ bq,
    const float* __restrict__ We,
    float* __restrict__ Wqe, float* __restrict__ bqe)
{
    __shared__ float WeL[ED * (D + 1)];
    const int tid = threadIdx.x;
    for (int i = tid; i < ED * D; i += 128) {
        int c = i >> 7, j = i & (D - 1);
        WeL[c * (D + 1) + j] = We[i];
    }
    __syncthreads();
    const int c = tid & 63;
    if (blockIdx.x == 64) {
        if (tid < 64) {
            float acc = 0.f;
            for (int j = 0; j < D; ++j) acc += bq[j] * WeL[c * (D + 1) + j];
            bqe[c] = acc;
        }
        return;
    }
    const int ii = blockIdx.x * 2 + (tid >> 6);
    const float* wrow = Wq + (size_t)ii * D;
    float acc = 0.f;
#pragma unroll 4
    for (int j = 0; j < D; ++j) acc += wrow[j] * WeL[c * (D + 1) + j];
    Wqe[(size_t)ii * ED + c] = acc;
}

// ---------------- pack weights into MFMA B-fragment bf16 layout ------------
__global__ __launch_bounds__(256) void pack_weights_kernel(
    const float* __restrict__ Wq, const float* __restrict__ Wk,
    const float* __restrict__ Wv, const float* __restrict__ Ws,
    const float* __restrict__ Wqe,
    const float* __restrict__ bq, const float* __restrict__ bk,
    const float* __restrict__ bv, const float* __restrict__ bs,
    const float* __restrict__ bqe,
    unsigned short* __restrict__ Bp, float* __restrict__ bias)
{
    const int i = blockIdx.x * 256 + threadIdx.x;
    if (i < 9216) {
        const int kb = i / 2304;
        const int rem = i - kb * 2304;
        const int n = rem >> 2;
        const int quad = rem & 3;
        const int k0 = kb * 32 + quad * 8;
        const float* src; int cl, stride;
        if (n < 128)      { src = Wq;  cl = n;       stride = 128; }
        else if (n < 256) { src = Wk;  cl = n - 128; stride = 128; }
        else if (n < 384) { src = Wv;  cl = n - 256; stride = 128; }
        else if (n < 512) { src = Ws;  cl = n - 384; stride = 128; }
        else              { src = Wqe; cl = n - 512; stride = 64;  }
        unsigned int w[4];
#pragma unroll
        for (int p = 0; p < 4; ++p) {
            unsigned short lo = f2bf(src[(size_t)(k0 + 2 * p) * stride + cl]);
            unsigned short hi = f2bf(src[(size_t)(k0 + 2 * p + 1) * stride + cl]);
            w[p] = (unsigned int)lo | ((unsigned int)hi << 16);
        }
        ((uint4*)Bp)[i] = make_uint4(w[0], w[1], w[2], w[3]);
    } else if (i < 9216 + 576) {
        const int c = i - 9216;
        float b;
        if (c < 128)      b = bq[c];
        else if (c < 256) b = bk[c - 128];
        else if (c < 384) b = bv[c - 256];
        else if (c < 512) b = bs[c - 384];
        else              b = bqe[c - 512];
        bias[c] = b;
    }
}

// ---------------- cast fp32 -> bf16 (8 elems / thread) ---------------------
__global__ __launch_bounds__(256) void cast_bf16_kernel(
    const float* __restrict__ x, unsigned short* __restrict__ xb, int n8)
{
    const int i = blockIdx.x * 256 + threadIdx.x;
    if (i >= n8) return;
    const float4 a = ((const float4*)x)[i * 2];
    const float4 b = ((const float4*)x)[i * 2 + 1];
    uint4 o;
    o.x = (unsigned int)f2bf(a.x) | ((unsigned int)f2bf(a.y) << 16);
    o.y = (unsigned int)f2bf(a.z) | ((unsigned int)f2bf(a.w) << 16);
    o.z = (unsigned int)f2bf(b.x) | ((unsigned int)f2bf(b.y) << 16);
    o.w = (unsigned int)f2bf(b.z) | ((unsigned int)f2bf(b.w) << 16);
    ((uint4*)xb)[i] = o;
}

// ---------------- MFMA pre-GEMM: [N x 128] @ [128 x 576] -------------------
// Outputs: q fp32, kv interleaved bf16 [N][256], skip fp32 (-> d_out), qe fp32
__global__ __launch_bounds__(256) void pre_mfma_kernel(
    const unsigned short* __restrict__ xb, const unsigned short* __restrict__ Bp,
    const float* __restrict__ bias,
    float* __restrict__ q, unsigned short* __restrict__ kvb,
    float* __restrict__ skip, float* __restrict__ qe, int n_nodes)
{
    const int wave = threadIdx.x >> 6, lane = threadIdx.x & 63;
    const int l16 = lane & 15, quad = lane >> 4;
    const int row0 = blockIdx.x * 64 + wave * 16;

    const unsigned short* xr = xb + (size_t)(row0 + l16) * 128 + quad * 8;
    bf16x8 A[4];
#pragma unroll
    for (int kb = 0; kb < 4; ++kb) A[kb] = *(const bf16x8*)(xr + kb * 32);

    const int t0 = blockIdx.y * 18;
    f32x4 acc[18];
#pragma unroll
    for (int t = 0; t < 18; ++t) acc[t] = (f32x4){0.f, 0.f, 0.f, 0.f};

#pragma unroll
    for (int t = 0; t < 18; ++t) {
        const unsigned short* bp = Bp + (size_t)((((t0 + t) * 16 + l16) * 4 + quad)) * 8;
#pragma unroll
        for (int kb = 0; kb < 4; ++kb) {
            bf16x8 B = *(const bf16x8*)(bp + kb * 18432);
            acc[t] = __builtin_amdgcn_mfma_f32_16x16x32_bf16(A[kb], B, acc[t], 0, 0, 0);
        }
    }

#pragma unroll
    for (int t = 0; t < 18; ++t) {
        const int c = (t0 + t) * 16 + l16;
        const float bia = bias[c];
#pragma unroll
        for (int r = 0; r < 4; ++r) {
            const int gr = row0 + quad * 4 + r;
            if (gr >= n_nodes) continue;
            const float val = acc[t][r] + bia;
            if (c < 128)      q[(size_t)gr * D + c] = val;
            else if (c < 256) kvb[(size_t)gr * 256 + (c - 128)] = f2bf(val);
            else if (c < 384) kvb[(size_t)gr * 256 + 128 + (c - 256)] = f2bf(val);
            else if (c < 512) skip[(size_t)gr * D + (c - 384)] = val;
            else              qe[(size_t)gr * ED + (c - 512)] = val;
        }
    }
}

// ---------------- CSR build ------------------------------------------------
__global__ __launch_bounds__(256) void hist_kernel(
    const int* __restrict__ ei, int* __restrict__ cnt, int nE)
{
    int e = blockIdx.x * 256 + threadIdx.x;
    if (e >= nE) return;
    atomicAdd(&cnt[ei[nE + e]], 1);
}

__global__ __launch_bounds__(256) void scan1_kernel(
    const int* __restrict__ cnt, int* __restrict__ offs,
    int* __restrict__ blksum, int n)
{
    __shared__ int tmp[256];
    const int t = threadIdx.x;
    const int base = blockIdx.x * 1024 + t * 4;
    int v0 = (base + 0 < n) ? cnt[base + 0] : 0;
    int v1 = (base + 1 < n) ? cnt[base + 1] : 0;
    int v2 = (base + 2 < n) ? cnt[base + 2] : 0;
    int v3 = (base + 3 < n) ? cnt[base + 3] : 0;
    const int s = v0 + v1 + v2 + v3;
    tmp[t] = s;
    __syncthreads();
    for (int ofs = 1; ofs < 256; ofs <<= 1) {
        int val = (t >= ofs) ? tmp[t - ofs] : 0;
        __syncthreads();
        tmp[t] += val;
        __syncthreads();
    }
    const int excl = tmp[t] - s;
    if (base + 0 < n) offs[base + 0] = excl;
    if (base + 1 < n) offs[base + 1] = excl + v0;
    if (base + 2 < n) offs[base + 2] = excl + v0 + v1;
    if (base + 3 < n) offs[base + 3] = excl + v0 + v1 + v2;
    if (t == 255) blksum[blockIdx.x] = tmp[255];
}

__global__ __launch_bounds__(64) void scan2_kernel(
    int* __restrict__ offs, int* __restrict__ cursor,
    const int* __restrict__ blksum, int n, int nblk)
{
    const int t = threadIdx.x;
    const int b = blockIdx.x;
    int vb = (t < b) ? blksum[t] : 0;
    int va = (t < nblk) ? blksum[t] : 0;
#pragma unroll
    for (int o = 32; o; o >>= 1) { vb += __shfl_xor(vb, o, 64); va += __shfl_xor(va, o, 64); }
    const int boff = vb;
    for (int i = b * 1024 + t; i < (b + 1) * 1024 && i < n; i += 64) {
        int val = offs[i] + boff;
        offs[i] = val;
        cursor[i] = val;
    }
    if (b == 0 && t == 0) offs[n] = va;
}

__global__ __launch_bounds__(256) void scatter_kernel(
    const int* __restrict__ ei, int* __restrict__ cursor,
    int2* __restrict__ csr, int nE)
{
    int e = blockIdx.x * 256 + threadIdx.x;
    if (e >= nE) return;
    int dd = ei[nE + e];
    int slot = atomicAdd(&cursor[dd], 1);
    csr[slot] = make_int2(ei[e], e);
}

// ---------------- fused per-node attention ---------------------------------
// persistent waves; 4 edges per iteration (16 lanes per edge); bf16 kv + ea;
// no max-subtraction (|alpha| <~ 7 for this data); prefetch next 4 edges.
template<bool L1>
__global__ __launch_bounds__(512) void node_attn_kernel(
    const int* __restrict__ rowptr, const int2* __restrict__ csr,
    const unsigned short* __restrict__ eab, const float* __restrict__ q,
    const unsigned short* __restrict__ kvb, const float* __restrict__ qe,
    const float* __restrict__ skip, const float* __restrict__ We,
    float* __restrict__ outf, unsigned short* __restrict__ outb,
    int n_nodes, int nwaves)
{
    __shared__ float WeS[ED * D];   // 32 KB
    const int tid = threadIdx.x;
    for (int i = tid; i < ED * D; i += 512) WeS[i] = We[i];
    __syncthreads();

    const int lane = tid & 63;
    const int grp = lane >> 4, l16 = lane & 15;
    const int wid = blockIdx.x * 8 + (tid >> 6);

    for (int d = wid; d < n_nodes; d += nwaves) {
        const int beg = rowptr[d], end = rowptr[d + 1];
        const float4* qp = (const float4*)(q + (size_t)d * D);
        const float4 qa = qp[l16 * 2], qb = qp[l16 * 2 + 1];
        const float4 qe4 = ((const float4*)(qe + (size_t)d * ED))[l16];

        float a0=0,a1=0,a2=0,a3=0,a4=0,a5=0,a6=0,a7=0;
        float t0=0,t1=0,t2=0,t3=0, lsum=0;

        uint4 pk, pv; uint2 pe; bool pvalid = false;
        auto pref = [&](int i) {
            const int idx = i + grp;
            pvalid = idx < end;
            const int2 se = csr[pvalid ? idx : beg];
            const uint4* kvp = (const uint4*)(kvb + (size_t)se.x * 256);
            pk = kvp[l16];
            pv = kvp[16 + l16];
            pe = ((const uint2*)(eab + (size_t)se.y * ED))[l16];
        };

        if (beg < end) {
            pref(beg);
            for (int i = beg; i < end; i += 4) {
                const bool cval = pvalid;
                const uint4 ck = pk, cv = pv;
                const uint2 ce = pe;
                if (i + 4 < end) pref(i + 4);
                float k0,k1,k2,k3,k4,k5,k6,k7, e0,e1,e2,e3;
                BF2(ck.x, k0, k1); BF2(ck.y, k2, k3);
                BF2(ck.z, k4, k5); BF2(ck.w, k6, k7);
                BF2(ce.x, e0, e1); BF2(ce.y, e2, e3);
                float p = k0*qa.x + k1*qa.y + k2*qa.z + k3*qa.w
                        + k4*qb.x + k5*qb.y + k6*qb.z + k7*qb.w
                        + e0*qe4.x + e1*qe4.y + e2*qe4.z + e3*qe4.w;
                p += __shfl_xor(p, 8, 64);
                p += __shfl_xor(p, 4, 64);
                p += __shfl_xor(p, 2, 64);
                p += __shfl_xor(p, 1, 64);
                const float w = cval ? __expf(p * 0.08838834764831845f) : 0.f;
                float v0,v1,v2,v3,v4,v5,v6,v7;
                BF2(cv.x, v0, v1); BF2(cv.y, v2, v3);
                BF2(cv.z, v4, v5); BF2(cv.w, v6, v7);
                a0 += w*v0; a1 += w*v1; a2 += w*v2; a3 += w*v3;
                a4 += w*v4; a5 += w*v5; a6 += w*v6; a7 += w*v7;
                t0 += w*e0; t1 += w*e1; t2 += w*e2; t3 += w*e3;
                lsum += w;
            }
        }
        // merge the 4 groups
#pragma unroll
        for (int off = 16; off <= 32; off <<= 1) {
            a0 += __shfl_xor(a0, off, 64); a1 += __shfl_xor(a1, off, 64);
            a2 += __shfl_xor(a2, off, 64); a3 += __shfl_xor(a3, off, 64);
            a4 += __shfl_xor(a4, off, 64); a5 += __shfl_xor(a5, off, 64);
            a6 += __shfl_xor(a6, off, 64); a7 += __shfl_xor(a7, off, 64);
            t0 += __shfl_xor(t0, off, 64); t1 += __shfl_xor(t1, off, 64);
            t2 += __shfl_xor(t2, off, 64); t3 += __shfl_xor(t3, off, 64);
            lsum += __shfl_xor(lsum, off, 64);
        }
        const float inv = 1.f / fmaxf(lsum, 1e-16f);
        a0*=inv; a1*=inv; a2*=inv; a3*=inv; a4*=inv; a5*=inv; a6*=inv; a7*=inv;
        t0*=inv; t1*=inv; t2*=inv; t3*=inv;
        const float tt[4] = {t0, t1, t2, t3};

        // epilogue: groups split the 64 t-columns (16 each), merge after
        float o0=0,o1=0,o2=0,o3=0,o4=0,o5=0,o6=0,o7=0;
#pragma unroll
        for (int cc = 0; cc < 16; ++cc) {
            const int c = grp * 16 + cc;
            const float tc = __shfl(tt[cc & 3], c >> 2, 64);
            const float4 w0 = ((const float4*)(WeS + c * D))[l16 * 2];
            const float4 w1 = ((const float4*)(WeS + c * D))[l16 * 2 + 1];
            o0 += tc*w0.x; o1 += tc*w0.y; o2 += tc*w0.z; o3 += tc*w0.w;
            o4 += tc*w1.x; o5 += tc*w1.y; o6 += tc*w1.z; o7 += tc*w1.w;
        }
#pragma unroll
        for (int off = 16; off <= 32; off <<= 1) {
            o0 += __shfl_xor(o0, off, 64); o1 += __shfl_xor(o1, off, 64);
            o2 += __shfl_xor(o2, off, 64); o3 += __shfl_xor(o3, off, 64);
            o4 += __shfl_xor(o4, off, 64); o5 += __shfl_xor(o5, off, 64);
            o6 += __shfl_xor(o6, off, 64); o7 += __shfl_xor(o7, off, 64);
        }

        if (grp == 0) {
            const float4* sp = (const float4*)(skip + (size_t)d * D);
            const float4 s0 = sp[l16 * 2], s1 = sp[l16 * 2 + 1];
            float r0 = a0 + s0.x + o0, r1 = a1 + s0.y + o1;
            float r2 = a2 + s0.z + o2, r3 = a3 + s0.w + o3;
            float r4 = a4 + s1.x + o4, r5 = a5 + s1.y + o5;
            float r6 = a6 + s1.z + o6, r7 = a7 + s1.w + o7;
            if (L1) {
                r0 = fmaxf(r0, 0.f); r1 = fmaxf(r1, 0.f);
                r2 = fmaxf(r2, 0.f); r3 = fmaxf(r3, 0.f);
                r4 = fmaxf(r4, 0.f); r5 = fmaxf(r5, 0.f);
                r6 = fmaxf(r6, 0.f); r7 = fmaxf(r7, 0.f);
                uint4 o;
                o.x = (unsigned int)f2bf(r0) | ((unsigned int)f2bf(r1) << 16);
                o.y = (unsigned int)f2bf(r2) | ((unsigned int)f2bf(r3) << 16);
                o.z = (unsigned int)f2bf(r4) | ((unsigned int)f2bf(r5) << 16);
                o.w = (unsigned int)f2bf(r6) | ((unsigned int)f2bf(r7) << 16);
                ((uint4*)(outb + (size_t)d * D))[l16] = o;
            } else {
                float4* op = (float4*)(outf + (size_t)d * D);
                op[l16 * 2]     = make_float4(r0, r1, r2, r3);
                op[l16 * 2 + 1] = make_float4(r4, r5, r6, r7);
            }
        }
    }
}

// ---------------------------------------------------------------------------
extern "C" void kernel_launch(void* const* d_in, const int* in_sizes, int n_in,
                              void* d_out, int out_size, void* d_ws, size_t ws_size,
                              hipStream_t stream) {
    const float* x   = (const float*)d_in[0];
    const int*   ei  = (const int*)d_in[1];
    const float* ea  = (const float*)d_in[2];
    const float* Wq1 = (const float*)d_in[3];  const float* bq1 = (const float*)d_in[4];
    const float* Wk1 = (const float*)d_in[5];  const float* bk1 = (const float*)d_in[6];
    const float* Wv1 = (const float*)d_in[7];  const float* bv1 = (const float*)d_in[8];
    const float* We1 = (const float*)d_in[9];
    const float* Ws1 = (const float*)d_in[10]; const float* bs1 = (const float*)d_in[11];
    const float* Wq2 = (const float*)d_in[12]; const float* bq2 = (const float*)d_in[13];
    const float* Wk2 = (const float*)d_in[14]; const float* bk2 = (const float*)d_in[15];
    const float* Wv2 = (const float*)d_in[16]; const float* bv2 = (const float*)d_in[17];
    const float* We2 = (const float*)d_in[18];
    const float* Ws2 = (const float*)d_in[19]; const float* bs2 = (const float*)d_in[20];

    const int N_ = in_sizes[0] / D;
    const int E_ = in_sizes[1] / 2;
    const int Npad = ((N_ + 63) / 64) * 64;

    // workspace layout
    float* q    = (float*)d_ws;
    float* qe   = q + (size_t)Npad * D;
    unsigned short* kvb = (unsigned short*)(qe + (size_t)Npad * ED);  // [Npad][256]
    unsigned short* xb  = kvb + (size_t)Npad * 256;                   // [Npad][128]
    unsigned short* eab = xb + (size_t)Npad * D;                      // [E][64]
    unsigned short* Bp1 = eab + (size_t)E_ * ED;
    unsigned short* Bp2 = Bp1 + 73728;
    float* bias1 = (float*)(Bp2 + 73728);
    float* bias2 = bias1 + 576;
    float* Wqe1  = bias2 + 576;
    float* bqe1  = Wqe1 + D * ED;
    float* Wqe2  = bqe1 + ED;
    float* bqe2  = Wqe2 + D * ED;
    int* cnt    = (int*)(bqe2 + ED);
    int* offs   = cnt  + N_;
    int* blksum = offs + N_ + 1;
    int2* csr   = (int2*)(blksum + 64);
    float* skip = (float*)d_out;       // skip buffer lives in d_out (both layers)
    float* out  = (float*)d_out;

    const int eblk256 = (E_ + 255) / 256;
    const int sblk    = (N_ + 1023) / 1024;
    const int gpre    = Npad / 64;
    const int ablk    = 1024;
    const int nwaves  = ablk * 8;

    // ---- CSR build (shared by both layers) ----
    hipMemsetAsync(cnt, 0, (size_t)N_ * sizeof(int), stream);
    hist_kernel<<<eblk256, 256, 0, stream>>>(ei, cnt, E_);
    scan1_kernel<<<sblk, 256, 0, stream>>>(cnt, offs, blksum, N_);
    scan2_kernel<<<sblk, 64, 0, stream>>>(offs, cnt, blksum, N_, sblk);
    scatter_kernel<<<eblk256, 256, 0, stream>>>(ei, cnt, csr, E_);

    // ---- prep: fused weights, packs, casts ----
    fuse_we_kernel<<<65, 128, 0, stream>>>(Wq1, bq1, We1, Wqe1, bqe1);
    fuse_we_kernel<<<65, 128, 0, stream>>>(Wq2, bq2, We2, Wqe2, bqe2);
    pack_weights_kernel<<<39, 256, 0, stream>>>(Wq1, Wk1, Wv1, Ws1, Wqe1,
                                                bq1, bk1, bv1, bs1, bqe1, Bp1, bias1);
    pack_weights_kernel<<<39, 256, 0, stream>>>(Wq2, Wk2, Wv2, Ws2, Wqe2,
                                                bq2, bk2, bv2, bs2, bqe2, Bp2, bias2);
    cast_bf16_kernel<<<(N_ * D / 8 + 255) / 256, 256, 0, stream>>>(x, xb, N_ * D / 8);
    cast_bf16_kernel<<<(E_ * ED / 8 + 255) / 256, 256, 0, stream>>>(ea, eab, E_ * ED / 8);

    // ---- layer 1 ----
    pre_mfma_kernel<<<dim3(gpre, 2), 256, 0, stream>>>(xb, Bp1, bias1,
                                                       q, kvb, skip, qe, N_);
    node_attn_kernel<true><<<ablk, 512, 0, stream>>>(offs, csr, eab, q, kvb, qe, skip,
                                                     We1, nullptr, xb, N_, nwaves);
    // ---- layer 2 (h lives as bf16 in xb) ----
    pre_mfma_kernel<<<dim3(gpre, 2), 256, 0, stream>>>(xb, Bp2, bias2,
                                                       q, kvb, skip, qe, N_);
    node_attn_kernel<false><<<ablk, 512, 0, stream>>>(offs, csr, eab, q, kvb, qe, skip,
                                                      We2, out, nullptr, N_, nwaves);
}